// Round 4
// baseline (263.730 us; speedup 1.0000x reference)
//
#include <hip/hip_runtime.h>

#define N_NODES 50000
#define N_EDGES 600000
#define HDIM 128
#define NGRAPH 500
#define NCLASS 10
#define BN_EPS 1e-5f
#define KSLOT 64
#define KSTRIDE 72   // u16 slots; 8-slot pad keeps the 8-edge batch loads in-bounds
#define NBLK 3125    // 50000 / 16 nodes per conv block

typedef short short8 __attribute__((ext_vector_type(8)));
typedef unsigned short ushort8v __attribute__((ext_vector_type(8)));
typedef float floatx4 __attribute__((ext_vector_type(4)));

__device__ __forceinline__ float bf2f(unsigned short u) {
    unsigned int v = ((unsigned int)u) << 16;
    return __uint_as_float(v);
}
__device__ __forceinline__ unsigned short f2bf(float f) {
    unsigned int u = __float_as_uint(f);
    unsigned int r = (u + 0x7fffu + ((u >> 16) & 1u)) >> 16;
    return (unsigned short)r;
}

// ---------------- pre-kernel: zero cnt (must precede the scatter blocks in k_setup) ----
__global__ void k_zero(int* __restrict__ cnt) {
    int i = blockIdx.x * blockDim.x + threadIdx.x;
    if (i < N_NODES) cnt[i] = 0;
}

// ---------------- fused setup: scatter (interleaved) | castx | prepW | offsets | ep ----
// Scatter is atomic-throughput-bound (~43us, invariant across 3 structural variants);
// all streaming roles hide under it. Branchless 8-deep form kept.
#define ILV 24
#define NB_SCAT 293           // 75000 8-edge threads
#define NB_CAST 6250
#define NB_PREPW 256
#define NB_OFF 197            // graph row-offset build (50001 indices)
#define NB_SETUP (NB_SCAT * ILV)   // 7032; non-scatter capacity 6739 >= 6704 used

// W packs (4 x 16384 bf16), ALL standard B-operand layout, frag index:
//   (((ct*4+s)*4+q)*16+m)*8+j ; k = s*32 + q*8 + j ; val = W[k][ct*16+m]
//   (w=3: * g2[k]*rsqrt(v2[k]+eps))
// NOTE: pi-permuted layout is ONLY valid when the A-fragment is built in the same
// pi order (old per-lane repack). htile A-frags are read in standard order, so the
// B packs must be standard too (round-3 bug: permuted one operand only).
__global__ void k_setup(const float* __restrict__ x, unsigned short* __restrict__ xb,
                        const int* __restrict__ src, const int* __restrict__ dst,
                        int* __restrict__ cnt, unsigned short* __restrict__ adj,
                        const int* __restrict__ batch, int* __restrict__ off,
                        const float* __restrict__ W1a, const float* __restrict__ W1b,
                        const float* __restrict__ W2a, const float* __restrict__ W2b,
                        unsigned short* __restrict__ wpack,
                        const float* __restrict__ b1a, const float* __restrict__ g1,
                        const float* __restrict__ be1, const float* __restrict__ m1,
                        const float* __restrict__ v1, const float* __restrict__ b1b,
                        const float* __restrict__ b2a, const float* __restrict__ g2,
                        const float* __restrict__ be2, const float* __restrict__ m2,
                        const float* __restrict__ v2, const float* __restrict__ b2b,
                        float* __restrict__ ep) {
    int b = blockIdx.x;
    int t = threadIdx.x;
    if (b % ILV == 0) {
        int i8 = (b / ILV) * 256 + t;      // 8 edges per thread
        if (i8 < N_EDGES / 8) {
            const int4* s4p = (const int4*)src;
            const int4* d4p = (const int4*)dst;
            int4 sa = s4p[i8 * 2], sb = s4p[i8 * 2 + 1];
            int4 da = d4p[i8 * 2], db = d4p[i8 * 2 + 1];
            int p0 = atomicAdd(&cnt[da.x], 1);
            int p1 = atomicAdd(&cnt[da.y], 1);
            int p2 = atomicAdd(&cnt[da.z], 1);
            int p3 = atomicAdd(&cnt[da.w], 1);
            int p4 = atomicAdd(&cnt[db.x], 1);
            int p5 = atomicAdd(&cnt[db.y], 1);
            int p6 = atomicAdd(&cnt[db.z], 1);
            int p7 = atomicAdd(&cnt[db.w], 1);
            adj[da.x * KSTRIDE + (p0 < KSLOT ? p0 : KSTRIDE - 1)] = (unsigned short)sa.x;
            adj[da.y * KSTRIDE + (p1 < KSLOT ? p1 : KSTRIDE - 1)] = (unsigned short)sa.y;
            adj[da.z * KSTRIDE + (p2 < KSLOT ? p2 : KSTRIDE - 1)] = (unsigned short)sa.z;
            adj[da.w * KSTRIDE + (p3 < KSLOT ? p3 : KSTRIDE - 1)] = (unsigned short)sa.w;
            adj[db.x * KSTRIDE + (p4 < KSLOT ? p4 : KSTRIDE - 1)] = (unsigned short)sb.x;
            adj[db.y * KSTRIDE + (p5 < KSLOT ? p5 : KSTRIDE - 1)] = (unsigned short)sb.y;
            adj[db.z * KSTRIDE + (p6 < KSLOT ? p6 : KSTRIDE - 1)] = (unsigned short)sb.z;
            adj[db.w * KSTRIDE + (p7 < KSLOT ? p7 : KSTRIDE - 1)] = (unsigned short)sb.w;
        }
        return;
    }
    b = b - b / ILV - 1;                   // non-scatter rank
    if (b < NB_CAST) {
        int i = b * 256 + t;   // over 1.6M float4
        float4 v = ((const float4*)x)[i];
        ushort4 o;
        o.x = f2bf(v.x); o.y = f2bf(v.y); o.z = f2bf(v.z); o.w = f2bf(v.w);
        ((ushort4*)xb)[i] = o;
        return;
    }
    b -= NB_CAST;
    if (b < NB_PREPW) {
        int e = b * 256 + t;               // 0..65535
        int w = e >> 14;
        int s_ = e & 16383;
        int j = s_ & 7;
        int m = (s_ >> 3) & 15;
        int q = (s_ >> 7) & 3;
        int ks = (s_ >> 9) & 3;
        int ct = (s_ >> 11) & 7;
        int n = ct * 16 + m;
        int k = ks * 32 + q * 8 + j;       // STANDARD B layout, all packs
        float scale = (w == 3) ? g2[k] * rsqrtf(v2[k] + BN_EPS) : 1.f;
        const float* W = (w == 0) ? W1a : (w == 1) ? W1b : (w == 2) ? W2a : W2b;
        wpack[e] = f2bf(W[k * 128 + n] * scale);
        return;
    }
    b -= NB_PREPW;
    if (b < NB_OFF) {
        int i = b * 256 + t;               // 0..50431; valid i in [0, N]
        if (i <= N_NODES) {
            int glo = (i == 0) ? 0 : batch[i - 1] + 1;
            int ghi = (i == N_NODES) ? NGRAPH : batch[i];   // inclusive
            for (int g = glo; g <= ghi; g++) off[g] = i;
        }
        return;
    }
    b -= NB_OFF;
    if (b != 0) return;
    // ep layout: epi[conv][{P,Q}][128] at conv*256, epf[conv][128] at 512+conv*128
    if (t < 128) {
        int j = t;
        float s1 = g1[j] * rsqrtf(v1[j] + BN_EPS);
        ep[0 * 256 + 0 + j]   = s1;
        ep[0 * 256 + 128 + j] = (b1a[j] - m1[j]) * s1 + be1[j];
        ep[1 * 256 + 0 + j]   = 1.f;
        ep[1 * 256 + 128 + j] = b2a[j];
        ep[512 + j] = b1b[j];
        float acc = b2b[j];
        for (int k = 0; k < 128; k++) {
            float s2k = g2[k] * rsqrtf(v2[k] + BN_EPS);
            acc += (be2[k] - m2[k] * s2k) * W2b[k * 128 + j];
        }
        ep[512 + 128 + j] = acc;
    }
}

// ---------------- fused conv: gather + MLP(2 gemms) + partial pooling ----------------
// Block = 16 nodes, 256 threads. Phases:
//  G: gather (verbatim proven k_agg geometry: 16 lanes/node, 8-deep) -> swizzled LDS htile
//  M1: gemm Wa (16x16x32 bf16 MFMA, A from htile std order, B from LDS Wl std order),
//      mid epilogue (P,Q) -> htile bounce; restage Wl <- Wb
//  M2: gemm Wb, final epilogue (Qf, relu)
//  store h rows (conv1 only), per-block per-graph f32 partial pools (no atomics)
// LDS = 32K(Wl) + 4K(htile) + 4K(ps) = 40KB exactly -> 4 blocks/CU; gather overlap
// across blocks hides MFMA phases in the gather's latency shadow.
__global__ __launch_bounds__(256, 4) void k_conv(const unsigned short* __restrict__ X,
                                                 const int* __restrict__ cnt,
                                                 const unsigned short* __restrict__ adj,
                                                 const unsigned short* __restrict__ WaP,
                                                 const unsigned short* __restrict__ WbP,
                                                 const float* __restrict__ epi,   // P[128],Q[128]
                                                 const float* __restrict__ epf,   // Qf[128]
                                                 const int* __restrict__ batch,
                                                 float* __restrict__ partial,     // [NBLK*2*128]
                                                 int* __restrict__ pgid,          // [NBLK*2]
                                                 unsigned short* __restrict__ Out) {
    __shared__ unsigned short Wl[16384];     // 32KB, Wa then Wb
    __shared__ unsigned short htile[2048];   // 16x128 bf16, row-XOR swizzled
    __shared__ float ps[2][4][128];          // 4KB partial-pool scratch
    int t = threadIdx.x;
    int base = blockIdx.x * 16;

    // stage Wa into LDS (loads issue before gather; latency shared)
    #pragma unroll
    for (int i = 0; i < 8; i++) {
        int c = t + 256 * i;
        *(short8*)(&Wl[c * 8]) = *(const short8*)(WaP + c * 8);
    }

    // ---- gather phase (verbatim k_agg core) ----
    {
        int node_l = t >> 4;
        int m = t & 15;
        int node = base + node_l;
        int len = cnt[node];
        if (len > KSLOT) len = KSLOT;
        const unsigned short* ad = adj + node * KSTRIDE;
        ushort8v ra = *(const ushort8v*)(ad);
        float self[8];
        {
            short8 sv = *(const short8*)(X + (size_t)node * 128 + m * 8);
            #pragma unroll
            for (int j = 0; j < 8; j++) self[j] = bf2f((unsigned short)sv[j]);
        }
        float acc[8];
        #pragma unroll
        for (int j = 0; j < 8; j++) acc[j] = self[j];
        int nb = (len + 7) >> 3;
        for (int bb = 0; bb < nb; bb++) {
            int i = bb * 8;
            ushort8v na = *(const ushort8v*)(ad + i + 8);
            int u0 = (i + 0 < len) ? (int)ra[0] : node;
            int u1 = (i + 1 < len) ? (int)ra[1] : node;
            int u2 = (i + 2 < len) ? (int)ra[2] : node;
            int u3 = (i + 3 < len) ? (int)ra[3] : node;
            int u4 = (i + 4 < len) ? (int)ra[4] : node;
            int u5 = (i + 5 < len) ? (int)ra[5] : node;
            int u6 = (i + 6 < len) ? (int)ra[6] : node;
            int u7 = (i + 7 < len) ? (int)ra[7] : node;
            short8 f0 = *(const short8*)(X + (size_t)u0 * 128 + m * 8);
            short8 f1 = *(const short8*)(X + (size_t)u1 * 128 + m * 8);
            short8 f2 = *(const short8*)(X + (size_t)u2 * 128 + m * 8);
            short8 f3 = *(const short8*)(X + (size_t)u3 * 128 + m * 8);
            short8 f4 = *(const short8*)(X + (size_t)u4 * 128 + m * 8);
            short8 f5 = *(const short8*)(X + (size_t)u5 * 128 + m * 8);
            short8 f6 = *(const short8*)(X + (size_t)u6 * 128 + m * 8);
            short8 f7 = *(const short8*)(X + (size_t)u7 * 128 + m * 8);
            #pragma unroll
            for (int j = 0; j < 8; j++) {
                float a = bf2f((unsigned short)f0[j]) + bf2f((unsigned short)f1[j]) +
                          bf2f((unsigned short)f2[j]) + bf2f((unsigned short)f3[j]);
                float c = bf2f((unsigned short)f4[j]) + bf2f((unsigned short)f5[j]) +
                          bf2f((unsigned short)f6[j]) + bf2f((unsigned short)f7[j]);
                acc[j] += a + c;
            }
            ra = na;
        }
        float extra = (float)(nb * 8 - len);
        short8 hv;
        #pragma unroll
        for (int j = 0; j < 8; j++) hv[j] = (short)f2bf(acc[j] - extra * self[j]);
        // swizzled write: row node_l, in-row byte m*16, XOR row-bits into bits 4:6
        int hb = node_l * 256 + ((m * 16) ^ ((node_l & 7) << 4));
        *(short8*)((char*)htile + hb) = hv;
    }
    __syncthreads();

    // ---- gemm phase ----
    int lane = t & 63;
    int w = t >> 6;
    int q = lane >> 4;
    int mm = lane & 15;
    int lbase = lane * 8;

    // A-frags: a[s] = Hagg[row=mm][k = s*32 + q*8 + j], swizzled read (standard order)
    short8 a[4];
    #pragma unroll
    for (int s = 0; s < 4; s++)
        a[s] = *(const short8*)((char*)htile + mm * 256 + ((s * 64 + q * 16) ^ ((mm & 7) << 4)));

    floatx4 acc1[2];
    acc1[0] = (floatx4)0.f; acc1[1] = (floatx4)0.f;
    #pragma unroll
    for (int c = 0; c < 2; c++) {
        int ct = w * 2 + c;
        #pragma unroll
        for (int s = 0; s < 4; s++) {
            short8 wf = *(const short8*)(&Wl[(ct * 4 + s) * 512 + lbase]);
            acc1[c] = __builtin_amdgcn_mfma_f32_16x16x32_bf16(a[s], wf, acc1[c], 0, 0, 0);
        }
    }
    __syncthreads();   // htile + Wl(Wa) reads complete

    // mid epilogue -> htile (transposed bounce), restage Wb
    // acc1[c][r] = D[node = base + q*4 + r][feature = ct*16 + mm]
    #pragma unroll
    for (int c = 0; c < 2; c++) {
        int ct = w * 2 + c;
        int col = ct * 16 + mm;
        float P = epi[col], Q = epi[128 + col];
        #pragma unroll
        for (int r = 0; r < 4; r++) {
            int row = q * 4 + r;
            float v = fmaxf(fmaf(acc1[c][r], P, Q), 0.f);
            int byte = row * 256 + (((unsigned)(col * 2)) ^ ((row & 7) << 4));
            *(unsigned short*)((char*)htile + byte) = f2bf(v);
        }
    }
    #pragma unroll
    for (int i = 0; i < 8; i++) {
        int c = t + 256 * i;
        *(short8*)(&Wl[c * 8]) = *(const short8*)(WbP + c * 8);
    }
    __syncthreads();

    // gemm2: A-frags from h_mid tile (same standard-order pattern)
    #pragma unroll
    for (int s = 0; s < 4; s++)
        a[s] = *(const short8*)((char*)htile + mm * 256 + ((s * 64 + q * 16) ^ ((mm & 7) << 4)));

    floatx4 acc2[2];
    acc2[0] = (floatx4)0.f; acc2[1] = (floatx4)0.f;
    #pragma unroll
    for (int c = 0; c < 2; c++) {
        int ct = w * 2 + c;
        #pragma unroll
        for (int s = 0; s < 4; s++) {
            short8 wf = *(const short8*)(&Wl[(ct * 4 + s) * 512 + lbase]);
            acc2[c] = __builtin_amdgcn_mfma_f32_16x16x32_bf16(a[s], wf, acc2[c], 0, 0, 0);
        }
    }

    // final epilogue: relu(acc2 + Qf)
    #pragma unroll
    for (int c = 0; c < 2; c++) {
        int col = (w * 2 + c) * 16 + mm;
        float Qf = epf[col];
        #pragma unroll
        for (int r = 0; r < 4; r++) acc2[c][r] = fmaxf(acc2[c][r] + Qf, 0.f);
    }

    // h store (conv1 only: conv2's h2 is consumed entirely via partials)
    if (Out) {
        #pragma unroll
        for (int c = 0; c < 2; c++) {
            int col = (w * 2 + c) * 16 + mm;
            #pragma unroll
            for (int r = 0; r < 4; r++)
                Out[(size_t)(base + q * 4 + r) * 128 + col] = f2bf(acc2[c][r]);
        }
    }

    // per-block per-graph f32 partial pools (<=2 graphs per 16-node window)
    int g0 = batch[base];
    int g1b = batch[base + 15];
    int gs1 = (g1b != g0) ? g1b : -1;
    int mygid[4];
    #pragma unroll
    for (int r = 0; r < 4; r++) mygid[r] = batch[base + q * 4 + r];
    #pragma unroll
    for (int k = 0; k < 2; k++) {
        int gk = k ? gs1 : g0;
        #pragma unroll
        for (int c = 0; c < 2; c++) {
            float pv = 0.f;
            #pragma unroll
            for (int r = 0; r < 4; r++)
                if (mygid[r] == gk) pv += acc2[c][r];
            ps[k][q][(w * 2 + c) * 16 + mm] = pv;
        }
    }
    __syncthreads();
    {
        int kk = t >> 7, col = t & 127;
        float s = ps[kk][0][col] + ps[kk][1][col] + ps[kk][2][col] + ps[kk][3][col];
        partial[((size_t)blockIdx.x * 2 + kk) * 128 + col] = s;
        if (t == 0) pgid[blockIdx.x * 2] = g0;
        if (t == 1) pgid[blockIdx.x * 2 + 1] = gs1;
    }
}

// ---------------- head: pool partials per graph, then 2-layer MLP ----------------
__global__ void k_head(const int* __restrict__ off, const int* __restrict__ pgid,
                       const float* __restrict__ partial1, const float* __restrict__ partial2,
                       const float* __restrict__ Wl1, const float* __restrict__ bl1,
                       const float* __restrict__ Wl2, const float* __restrict__ bl2,
                       float* __restrict__ out) {
    int g = blockIdx.x;
    int t = threadIdx.x;   // 128
    __shared__ float zL[256];
    __shared__ float zm[64];
    float z1 = 0.f, z2 = 0.f;
    int r0 = off[g], r1 = off[g + 1];
    if (r1 > r0) {
        int b0 = r0 >> 4, b1 = (r1 - 1) >> 4;
        for (int b = b0; b <= b1; b++) {
            #pragma unroll
            for (int k = 0; k < 2; k++) {
                if (pgid[b * 2 + k] == g) {
                    z1 += partial1[((size_t)b * 2 + k) * 128 + t];
                    z2 += partial2[((size_t)b * 2 + k) * 128 + t];
                }
            }
        }
    }
    zL[t] = z1;
    zL[128 + t] = z2;
    __syncthreads();
    if (t < 64) {
        float acc = bl1[t];
        #pragma unroll 8
        for (int k = 0; k < 256; k++) acc = fmaf(zL[k], Wl1[k * 64 + t], acc);
        zm[t] = fmaxf(acc, 0.f);
    }
    __syncthreads();
    if (t < NCLASS) {
        float a = bl2[t];
        #pragma unroll
        for (int j = 0; j < 64; j++) a = fmaf(zm[j], Wl2[j * 10 + t], a);
        out[g * NCLASS + t] = a;
    }
}

// ---------------- launch ----------------

extern "C" void kernel_launch(void* const* d_in, const int* in_sizes, int n_in,
                              void* d_out, int out_size, void* d_ws, size_t ws_size,
                              hipStream_t stream) {
    const float* x   = (const float*)d_in[0];
    const int* eidx  = (const int*)d_in[1];
    const int* batch = (const int*)d_in[2];
    const float* W1a = (const float*)d_in[3];
    const float* b1a = (const float*)d_in[4];
    const float* g1  = (const float*)d_in[5];
    const float* be1 = (const float*)d_in[6];
    const float* m1  = (const float*)d_in[7];
    const float* v1  = (const float*)d_in[8];
    const float* W1b = (const float*)d_in[9];
    const float* b1b = (const float*)d_in[10];
    const float* W2a = (const float*)d_in[11];
    const float* b2a = (const float*)d_in[12];
    const float* g2  = (const float*)d_in[13];
    const float* be2 = (const float*)d_in[14];
    const float* m2  = (const float*)d_in[15];
    const float* v2  = (const float*)d_in[16];
    const float* W2b = (const float*)d_in[17];
    const float* b2b = (const float*)d_in[18];
    const float* Wl1 = (const float*)d_in[19];
    const float* bl1 = (const float*)d_in[20];
    const float* Wl2 = (const float*)d_in[21];
    const float* bl2 = (const float*)d_in[22];
    const int* srcv = eidx;            // edge_index row 0
    const int* dstv = eidx + N_EDGES;  // edge_index row 1

    char* ws = (char*)d_ws;
    size_t offb = 0;
    auto alloc = [&](size_t bytes) -> void* {
        void* p = ws + offb;
        offb = (offb + bytes + 255) & ~(size_t)255;
        return p;
    };
    int* cnt      = (int*)alloc(sizeof(int) * N_NODES);
    unsigned short* adj = (unsigned short*)alloc(sizeof(unsigned short) * (size_t)N_NODES * KSTRIDE);
    float* ep     = (float*)alloc(sizeof(float) * 768);
    unsigned short* wpack = (unsigned short*)alloc(sizeof(unsigned short) * 4 * 16384);
    unsigned short* xb    = (unsigned short*)alloc(sizeof(unsigned short) * (size_t)N_NODES * HDIM);
    unsigned short* bufC  = (unsigned short*)alloc(sizeof(unsigned short) * (size_t)N_NODES * HDIM);
    float* partial1 = (float*)alloc(sizeof(float) * (size_t)NBLK * 2 * 128);
    float* partial2 = (float*)alloc(sizeof(float) * (size_t)NBLK * 2 * 128);
    int* pgid     = (int*)alloc(sizeof(int) * NBLK * 2);
    int* goff     = (int*)alloc(sizeof(int) * (NGRAPH + 1));
    (void)ws_size; (void)in_sizes; (void)n_in; (void)out_size;

    float* outp = (float*)d_out;

    // zero cnt first (scatter inside k_setup depends on it)
    k_zero<<<dim3((N_NODES + 255) / 256), dim3(256), 0, stream>>>(cnt);
    // setup mega-kernel: interleaved scatter | cast | prepW | offsets | ep
    k_setup<<<dim3(NB_SETUP), dim3(256), 0, stream>>>(
        x, xb, srcv, dstv, cnt, adj, batch, goff, W1a, W1b, W2a, W2b, wpack,
        b1a, g1, be1, m1, v1, b1b, b2a, g2, be2, m2, v2, b2b, ep);

    // conv1: gather(xb) + MLP1 -> h1 (bufC) + partial1
    k_conv<<<dim3(NBLK), dim3(256), 0, stream>>>(
        xb, cnt, adj, wpack + 0 * 16384, wpack + 1 * 16384,
        ep + 0, ep + 512, batch, partial1, pgid, bufC);
    // conv2: gather(h1) + MLP2 -> partial2 (no h2 store)
    k_conv<<<dim3(NBLK), dim3(256), 0, stream>>>(
        bufC, cnt, adj, wpack + 2 * 16384, wpack + 3 * 16384,
        ep + 256, ep + 640, batch, partial2, pgid, nullptr);
    // head: per-graph pool of partials + 2-layer MLP
    k_head<<<dim3(NGRAPH), dim3(128), 0, stream>>>(
        goff, pgid, partial1, partial2, Wl1, bl1, Wl2, bl2, outp);
}

// Round 5
// 221.073 us; speedup vs baseline: 1.1930x; 1.1930x over previous
//
#include <hip/hip_runtime.h>

#define N_NODES 50000
#define N_EDGES 600000
#define HDIM 128
#define NGRAPH 500
#define NCLASS 10
#define BN_EPS 1e-5f
#define KSLOT 64
#define KSTRIDE 72   // u16 slots; 8-slot pad keeps the 8-edge batch loads in-bounds
#define NBLK 3125    // 50000 / 16 nodes per conv block

typedef short short8 __attribute__((ext_vector_type(8)));
typedef unsigned short ushort8v __attribute__((ext_vector_type(8)));
typedef float floatx4 __attribute__((ext_vector_type(4)));

__device__ __forceinline__ float bf2f(unsigned short u) {
    unsigned int v = ((unsigned int)u) << 16;
    return __uint_as_float(v);
}
__device__ __forceinline__ unsigned short f2bf(float f) {
    unsigned int u = __float_as_uint(f);
    unsigned int r = (u + 0x7fffu + ((u >> 16) & 1u)) >> 16;
    return (unsigned short)r;
}

// ---------------- pre-kernel: zero cnt (must precede the scatter blocks in k_setup) ----
__global__ void k_zero(int* __restrict__ cnt) {
    int i = blockIdx.x * blockDim.x + threadIdx.x;
    if (i < N_NODES) cnt[i] = 0;
}

// ---------------- fused setup: scatter (interleaved) | castx | prepW | offsets | ep ----
// Scatter is atomic-throughput-bound (~43us); all streaming roles hide under it.
// ILV MUST be coprime with 8: blocks map round-robin to the 8 XCDs by blockIdx, and
// ILV=24 put every scatter block (b%24==0 -> b%8==0) on XCD 0 -> 2x slowdown (round 4).
#define ILV 25
#define NB_SCAT 293           // 75000 8-edge threads
#define NB_CAST 6250
#define NB_PREPW 256
#define NB_OFF 197            // graph row-offset build (50001 indices)
#define NB_SETUP (NB_SCAT * ILV)   // 7325; non-scatter capacity 7032 >= 6704 used

// W packs (4 x 16384 bf16), ALL standard B-operand layout, frag index:
//   (((ct*4+s)*4+q)*16+m)*8+j ; k = s*32 + q*8 + j ; val = W[k][ct*16+m]
//   (w=3: * g2[k]*rsqrt(v2[k]+eps))
__global__ void k_setup(const float* __restrict__ x, unsigned short* __restrict__ xb,
                        const int* __restrict__ src, const int* __restrict__ dst,
                        int* __restrict__ cnt, unsigned short* __restrict__ adj,
                        const int* __restrict__ batch, int* __restrict__ off,
                        const float* __restrict__ W1a, const float* __restrict__ W1b,
                        const float* __restrict__ W2a, const float* __restrict__ W2b,
                        unsigned short* __restrict__ wpack,
                        const float* __restrict__ b1a, const float* __restrict__ g1,
                        const float* __restrict__ be1, const float* __restrict__ m1,
                        const float* __restrict__ v1, const float* __restrict__ b1b,
                        const float* __restrict__ b2a, const float* __restrict__ g2,
                        const float* __restrict__ be2, const float* __restrict__ m2,
                        const float* __restrict__ v2, const float* __restrict__ b2b,
                        float* __restrict__ ep) {
    int b = blockIdx.x;
    int t = threadIdx.x;
    if (b % ILV == 0) {
        int i8 = (b / ILV) * 256 + t;      // 8 edges per thread
        if (i8 < N_EDGES / 8) {
            const int4* s4p = (const int4*)src;
            const int4* d4p = (const int4*)dst;
            int4 sa = s4p[i8 * 2], sb = s4p[i8 * 2 + 1];
            int4 da = d4p[i8 * 2], db = d4p[i8 * 2 + 1];
            int p0 = atomicAdd(&cnt[da.x], 1);
            int p1 = atomicAdd(&cnt[da.y], 1);
            int p2 = atomicAdd(&cnt[da.z], 1);
            int p3 = atomicAdd(&cnt[da.w], 1);
            int p4 = atomicAdd(&cnt[db.x], 1);
            int p5 = atomicAdd(&cnt[db.y], 1);
            int p6 = atomicAdd(&cnt[db.z], 1);
            int p7 = atomicAdd(&cnt[db.w], 1);
            adj[da.x * KSTRIDE + (p0 < KSLOT ? p0 : KSTRIDE - 1)] = (unsigned short)sa.x;
            adj[da.y * KSTRIDE + (p1 < KSLOT ? p1 : KSTRIDE - 1)] = (unsigned short)sa.y;
            adj[da.z * KSTRIDE + (p2 < KSLOT ? p2 : KSTRIDE - 1)] = (unsigned short)sa.z;
            adj[da.w * KSTRIDE + (p3 < KSLOT ? p3 : KSTRIDE - 1)] = (unsigned short)sa.w;
            adj[db.x * KSTRIDE + (p4 < KSLOT ? p4 : KSTRIDE - 1)] = (unsigned short)sb.x;
            adj[db.y * KSTRIDE + (p5 < KSLOT ? p5 : KSTRIDE - 1)] = (unsigned short)sb.y;
            adj[db.z * KSTRIDE + (p6 < KSLOT ? p6 : KSTRIDE - 1)] = (unsigned short)sb.z;
            adj[db.w * KSTRIDE + (p7 < KSLOT ? p7 : KSTRIDE - 1)] = (unsigned short)sb.w;
        }
        return;
    }
    b = b - b / ILV - 1;                   // non-scatter rank
    if (b < NB_CAST) {
        int i = b * 256 + t;   // over 1.6M float4
        float4 v = ((const float4*)x)[i];
        ushort4 o;
        o.x = f2bf(v.x); o.y = f2bf(v.y); o.z = f2bf(v.z); o.w = f2bf(v.w);
        ((ushort4*)xb)[i] = o;
        return;
    }
    b -= NB_CAST;
    if (b < NB_PREPW) {
        int e = b * 256 + t;               // 0..65535
        int w = e >> 14;
        int s_ = e & 16383;
        int j = s_ & 7;
        int m = (s_ >> 3) & 15;
        int q = (s_ >> 7) & 3;
        int ks = (s_ >> 9) & 3;
        int ct = (s_ >> 11) & 7;
        int n = ct * 16 + m;
        int k = ks * 32 + q * 8 + j;       // STANDARD B layout, all packs
        float scale = (w == 3) ? g2[k] * rsqrtf(v2[k] + BN_EPS) : 1.f;
        const float* W = (w == 0) ? W1a : (w == 1) ? W1b : (w == 2) ? W2a : W2b;
        wpack[e] = f2bf(W[k * 128 + n] * scale);
        return;
    }
    b -= NB_PREPW;
    if (b < NB_OFF) {
        int i = b * 256 + t;               // 0..50431; valid i in [0, N]
        if (i <= N_NODES) {
            int glo = (i == 0) ? 0 : batch[i - 1] + 1;
            int ghi = (i == N_NODES) ? NGRAPH : batch[i];   // inclusive
            for (int g = glo; g <= ghi; g++) off[g] = i;
        }
        return;
    }
    b -= NB_OFF;
    if (b != 0) return;
    // ep layout: epi[conv][{P,Q}][128] at conv*256, epf[conv][128] at 512+conv*128
    if (t < 128) {
        int j = t;
        float s1 = g1[j] * rsqrtf(v1[j] + BN_EPS);
        ep[0 * 256 + 0 + j]   = s1;
        ep[0 * 256 + 128 + j] = (b1a[j] - m1[j]) * s1 + be1[j];
        ep[1 * 256 + 0 + j]   = 1.f;
        ep[1 * 256 + 128 + j] = b2a[j];
        ep[512 + j] = b1b[j];
        float acc = b2b[j];
        for (int k = 0; k < 128; k++) {
            float s2k = g2[k] * rsqrtf(v2[k] + BN_EPS);
            acc += (be2[k] - m2[k] * s2k) * W2b[k * 128 + j];
        }
        ep[512 + 128 + j] = acc;
    }
}

// ---------------- fused conv: gather + MLP(2 gemms) + partial pooling ----------------
// Block = 16 nodes, 256 threads. W fragments are read DIRECTLY from global (L2-hot
// 32KB packs): in this block geometry each W byte is consumed by exactly one wave's
// one MFMA, so LDS staging had zero reuse (round-4 lesson) and only cost 32KB LDS +
// a VGPR round-trip. LDS is now 8KB (htile + ps) -> occupancy set by VGPRs (~6
// waves/SIMD), restoring gather queue depth; blocks at different phases overlap
// gather latency with MFMA/VALU work.
__global__ __launch_bounds__(256) void k_conv(const unsigned short* __restrict__ X,
                                              const int* __restrict__ cnt,
                                              const unsigned short* __restrict__ adj,
                                              const unsigned short* __restrict__ WaP,
                                              const unsigned short* __restrict__ WbP,
                                              const float* __restrict__ epi,   // P[128],Q[128]
                                              const float* __restrict__ epf,   // Qf[128]
                                              const int* __restrict__ batch,
                                              float* __restrict__ partial,     // [NBLK*2*128]
                                              int* __restrict__ pgid,          // [NBLK*2]
                                              unsigned short* __restrict__ Out) {
    __shared__ unsigned short htile[2048];   // 16x128 bf16, row-XOR swizzled (4KB)
    __shared__ float ps[2][4][128];          // partial-pool scratch (4KB)
    int t = threadIdx.x;
    int base = blockIdx.x * 16;

    // ---- gather phase (verbatim k_agg core) ----
    {
        int node_l = t >> 4;
        int m = t & 15;
        int node = base + node_l;
        int len = cnt[node];
        if (len > KSLOT) len = KSLOT;
        const unsigned short* ad = adj + node * KSTRIDE;
        ushort8v ra = *(const ushort8v*)(ad);
        float self[8];
        {
            short8 sv = *(const short8*)(X + (size_t)node * 128 + m * 8);
            #pragma unroll
            for (int j = 0; j < 8; j++) self[j] = bf2f((unsigned short)sv[j]);
        }
        float acc[8];
        #pragma unroll
        for (int j = 0; j < 8; j++) acc[j] = self[j];
        int nb = (len + 7) >> 3;
        for (int bb = 0; bb < nb; bb++) {
            int i = bb * 8;
            ushort8v na = *(const ushort8v*)(ad + i + 8);
            int u0 = (i + 0 < len) ? (int)ra[0] : node;
            int u1 = (i + 1 < len) ? (int)ra[1] : node;
            int u2 = (i + 2 < len) ? (int)ra[2] : node;
            int u3 = (i + 3 < len) ? (int)ra[3] : node;
            int u4 = (i + 4 < len) ? (int)ra[4] : node;
            int u5 = (i + 5 < len) ? (int)ra[5] : node;
            int u6 = (i + 6 < len) ? (int)ra[6] : node;
            int u7 = (i + 7 < len) ? (int)ra[7] : node;
            short8 f0 = *(const short8*)(X + (size_t)u0 * 128 + m * 8);
            short8 f1 = *(const short8*)(X + (size_t)u1 * 128 + m * 8);
            short8 f2 = *(const short8*)(X + (size_t)u2 * 128 + m * 8);
            short8 f3 = *(const short8*)(X + (size_t)u3 * 128 + m * 8);
            short8 f4 = *(const short8*)(X + (size_t)u4 * 128 + m * 8);
            short8 f5 = *(const short8*)(X + (size_t)u5 * 128 + m * 8);
            short8 f6 = *(const short8*)(X + (size_t)u6 * 128 + m * 8);
            short8 f7 = *(const short8*)(X + (size_t)u7 * 128 + m * 8);
            #pragma unroll
            for (int j = 0; j < 8; j++) {
                float a = bf2f((unsigned short)f0[j]) + bf2f((unsigned short)f1[j]) +
                          bf2f((unsigned short)f2[j]) + bf2f((unsigned short)f3[j]);
                float c = bf2f((unsigned short)f4[j]) + bf2f((unsigned short)f5[j]) +
                          bf2f((unsigned short)f6[j]) + bf2f((unsigned short)f7[j]);
                acc[j] += a + c;
            }
            ra = na;
        }
        float extra = (float)(nb * 8 - len);
        short8 hv;
        #pragma unroll
        for (int j = 0; j < 8; j++) hv[j] = (short)f2bf(acc[j] - extra * self[j]);
        // swizzled write: row node_l, in-row byte m*16, XOR row-bits into bits 4:6
        int hb = node_l * 256 + ((m * 16) ^ ((node_l & 7) << 4));
        *(short8*)((char*)htile + hb) = hv;
    }
    __syncthreads();

    // ---- gemm phase ----
    int lane = t & 63;
    int w = t >> 6;
    int q = lane >> 4;
    int mm = lane & 15;
    int lbase = lane * 8;

    // A-frags: a[s] = Hagg[row=mm][k = s*32 + q*8 + j], swizzled read (standard order)
    short8 a[4];
    #pragma unroll
    for (int s = 0; s < 4; s++)
        a[s] = *(const short8*)((char*)htile + mm * 256 + ((s * 64 + q * 16) ^ ((mm & 7) << 4)));

    floatx4 acc1[2];
    acc1[0] = (floatx4)0.f; acc1[1] = (floatx4)0.f;
    #pragma unroll
    for (int c = 0; c < 2; c++) {
        int ct = w * 2 + c;
        #pragma unroll
        for (int s = 0; s < 4; s++) {
            short8 wf = *(const short8*)(WaP + (ct * 4 + s) * 512 + lbase);
            acc1[c] = __builtin_amdgcn_mfma_f32_16x16x32_bf16(a[s], wf, acc1[c], 0, 0, 0);
        }
    }
    __syncthreads();   // htile reads complete before rewrite

    // mid epilogue -> htile (transposed bounce)
    // acc1[c][r] = D[node = base + q*4 + r][feature = ct*16 + mm]
    #pragma unroll
    for (int c = 0; c < 2; c++) {
        int ct = w * 2 + c;
        int col = ct * 16 + mm;
        float P = epi[col], Q = epi[128 + col];
        #pragma unroll
        for (int r = 0; r < 4; r++) {
            int row = q * 4 + r;
            float v = fmaxf(fmaf(acc1[c][r], P, Q), 0.f);
            int byte = row * 256 + (((unsigned)(col * 2)) ^ ((row & 7) << 4));
            *(unsigned short*)((char*)htile + byte) = f2bf(v);
        }
    }
    __syncthreads();

    // gemm2: A-frags from h_mid tile (same standard-order pattern)
    #pragma unroll
    for (int s = 0; s < 4; s++)
        a[s] = *(const short8*)((char*)htile + mm * 256 + ((s * 64 + q * 16) ^ ((mm & 7) << 4)));

    floatx4 acc2[2];
    acc2[0] = (floatx4)0.f; acc2[1] = (floatx4)0.f;
    #pragma unroll
    for (int c = 0; c < 2; c++) {
        int ct = w * 2 + c;
        #pragma unroll
        for (int s = 0; s < 4; s++) {
            short8 wf = *(const short8*)(WbP + (ct * 4 + s) * 512 + lbase);
            acc2[c] = __builtin_amdgcn_mfma_f32_16x16x32_bf16(a[s], wf, acc2[c], 0, 0, 0);
        }
    }

    // final epilogue: relu(acc2 + Qf)
    #pragma unroll
    for (int c = 0; c < 2; c++) {
        int col = (w * 2 + c) * 16 + mm;
        float Qf = epf[col];
        #pragma unroll
        for (int r = 0; r < 4; r++) acc2[c][r] = fmaxf(acc2[c][r] + Qf, 0.f);
    }

    // h store (conv1 only: conv2's h2 is consumed entirely via partials)
    if (Out) {
        #pragma unroll
        for (int c = 0; c < 2; c++) {
            int col = (w * 2 + c) * 16 + mm;
            #pragma unroll
            for (int r = 0; r < 4; r++)
                Out[(size_t)(base + q * 4 + r) * 128 + col] = f2bf(acc2[c][r]);
        }
    }

    // per-block per-graph f32 partial pools (<=2 graphs per 16-node window)
    int g0 = batch[base];
    int g1b = batch[base + 15];
    int gs1 = (g1b != g0) ? g1b : -1;
    int mygid[4];
    #pragma unroll
    for (int r = 0; r < 4; r++) mygid[r] = batch[base + q * 4 + r];
    #pragma unroll
    for (int k = 0; k < 2; k++) {
        int gk = k ? gs1 : g0;
        #pragma unroll
        for (int c = 0; c < 2; c++) {
            float pv = 0.f;
            #pragma unroll
            for (int r = 0; r < 4; r++)
                if (mygid[r] == gk) pv += acc2[c][r];
            ps[k][q][(w * 2 + c) * 16 + mm] = pv;
        }
    }
    __syncthreads();
    {
        int kk = t >> 7, col = t & 127;
        float s = ps[kk][0][col] + ps[kk][1][col] + ps[kk][2][col] + ps[kk][3][col];
        partial[((size_t)blockIdx.x * 2 + kk) * 128 + col] = s;
        if (t == 0) pgid[blockIdx.x * 2] = g0;
        if (t == 1) pgid[blockIdx.x * 2 + 1] = gs1;
    }
}

// ---------------- head: pool partials per graph, then 2-layer MLP ----------------
__global__ void k_head(const int* __restrict__ off, const int* __restrict__ pgid,
                       const float* __restrict__ partial1, const float* __restrict__ partial2,
                       const float* __restrict__ Wl1, const float* __restrict__ bl1,
                       const float* __restrict__ Wl2, const float* __restrict__ bl2,
                       float* __restrict__ out) {
    int g = blockIdx.x;
    int t = threadIdx.x;   // 128
    __shared__ float zL[256];
    __shared__ float zm[64];
    float z1 = 0.f, z2 = 0.f;
    int r0 = off[g], r1 = off[g + 1];
    if (r1 > r0) {
        int b0 = r0 >> 4, b1 = (r1 - 1) >> 4;
        for (int b = b0; b <= b1; b++) {
            #pragma unroll
            for (int k = 0; k < 2; k++) {
                if (pgid[b * 2 + k] == g) {
                    z1 += partial1[((size_t)b * 2 + k) * 128 + t];
                    z2 += partial2[((size_t)b * 2 + k) * 128 + t];
                }
            }
        }
    }
    zL[t] = z1;
    zL[128 + t] = z2;
    __syncthreads();
    if (t < 64) {
        float acc = bl1[t];
        #pragma unroll 8
        for (int k = 0; k < 256; k++) acc = fmaf(zL[k], Wl1[k * 64 + t], acc);
        zm[t] = fmaxf(acc, 0.f);
    }
    __syncthreads();
    if (t < NCLASS) {
        float a = bl2[t];
        #pragma unroll
        for (int j = 0; j < 64; j++) a = fmaf(zm[j], Wl2[j * 10 + t], a);
        out[g * NCLASS + t] = a;
    }
}

// ---------------- launch ----------------

extern "C" void kernel_launch(void* const* d_in, const int* in_sizes, int n_in,
                              void* d_out, int out_size, void* d_ws, size_t ws_size,
                              hipStream_t stream) {
    const float* x   = (const float*)d_in[0];
    const int* eidx  = (const int*)d_in[1];
    const int* batch = (const int*)d_in[2];
    const float* W1a = (const float*)d_in[3];
    const float* b1a = (const float*)d_in[4];
    const float* g1  = (const float*)d_in[5];
    const float* be1 = (const float*)d_in[6];
    const float* m1  = (const float*)d_in[7];
    const float* v1  = (const float*)d_in[8];
    const float* W1b = (const float*)d_in[9];
    const float* b1b = (const float*)d_in[10];
    const float* W2a = (const float*)d_in[11];
    const float* b2a = (const float*)d_in[12];
    const float* g2  = (const float*)d_in[13];
    const float* be2 = (const float*)d_in[14];
    const float* m2  = (const float*)d_in[15];
    const float* v2  = (const float*)d_in[16];
    const float* W2b = (const float*)d_in[17];
    const float* b2b = (const float*)d_in[18];
    const float* Wl1 = (const float*)d_in[19];
    const float* bl1 = (const float*)d_in[20];
    const float* Wl2 = (const float*)d_in[21];
    const float* bl2 = (const float*)d_in[22];
    const int* srcv = eidx;            // edge_index row 0
    const int* dstv = eidx + N_EDGES;  // edge_index row 1

    char* ws = (char*)d_ws;
    size_t offb = 0;
    auto alloc = [&](size_t bytes) -> void* {
        void* p = ws + offb;
        offb = (offb + bytes + 255) & ~(size_t)255;
        return p;
    };
    int* cnt      = (int*)alloc(sizeof(int) * N_NODES);
    unsigned short* adj = (unsigned short*)alloc(sizeof(unsigned short) * (size_t)N_NODES * KSTRIDE);
    float* ep     = (float*)alloc(sizeof(float) * 768);
    unsigned short* wpack = (unsigned short*)alloc(sizeof(unsigned short) * 4 * 16384);
    unsigned short* xb    = (unsigned short*)alloc(sizeof(unsigned short) * (size_t)N_NODES * HDIM);
    unsigned short* bufC  = (unsigned short*)alloc(sizeof(unsigned short) * (size_t)N_NODES * HDIM);
    float* partial1 = (float*)alloc(sizeof(float) * (size_t)NBLK * 2 * 128);
    float* partial2 = (float*)alloc(sizeof(float) * (size_t)NBLK * 2 * 128);
    int* pgid     = (int*)alloc(sizeof(int) * NBLK * 2);
    int* goff     = (int*)alloc(sizeof(int) * (NGRAPH + 1));
    (void)ws_size; (void)in_sizes; (void)n_in; (void)out_size;

    float* outp = (float*)d_out;

    // zero cnt first (scatter inside k_setup depends on it)
    k_zero<<<dim3((N_NODES + 255) / 256), dim3(256), 0, stream>>>(cnt);
    // setup mega-kernel: interleaved scatter | cast | prepW | offsets | ep
    k_setup<<<dim3(NB_SETUP), dim3(256), 0, stream>>>(
        x, xb, srcv, dstv, cnt, adj, batch, goff, W1a, W1b, W2a, W2b, wpack,
        b1a, g1, be1, m1, v1, b1b, b2a, g2, be2, m2, v2, b2b, ep);

    // conv1: gather(xb) + MLP1 -> h1 (bufC) + partial1
    k_conv<<<dim3(NBLK), dim3(256), 0, stream>>>(
        xb, cnt, adj, wpack + 0 * 16384, wpack + 1 * 16384,
        ep + 0, ep + 512, batch, partial1, pgid, bufC);
    // conv2: gather(h1) + MLP2 -> partial2 (no h2 store)
    k_conv<<<dim3(NBLK), dim3(256), 0, stream>>>(
        bufC, cnt, adj, wpack + 2 * 16384, wpack + 3 * 16384,
        ep + 256, ep + 640, batch, partial2, pgid, nullptr);
    // head: per-graph pool of partials + 2-layer MLP
    k_head<<<dim3(NGRAPH), dim3(128), 0, stream>>>(
        goff, pgid, partial1, partial2, Wl1, bl1, Wl2, bl2, outp);
}